// Round 8
// baseline (79.687 us; speedup 1.0000x reference)
//
#include <hip/hip_runtime.h>
#include <cmath>

// Noisy 8-qubit density-matrix sim, batch 32, depth 6 — single-kernel ADJOINT version.
// E_b = Tr(Λ†(Z0)·rho_b); rho_b = ⊗_q m_{b,q}. Backward-evolve O = Λ†(Z0) once through
// the reversed 4-phase trapezoid (D5 -> C8 -> B14 -> A15 stages), all inside ONE
// 16-block x 512-thread kernel with hand-rolled grid barriers (16 blocks always
// co-resident on 256 CUs). Cross-block buffer I/O via agent-scope atomics (MALL-
// coherent, safe across XCDs). Phase A's tile stays in LDS; expectation contracted
// in-block; block 0 does the final deterministic reduce. Launches: 1 memset + 1 kernel.

typedef float2 cplx;
#define BATCH 32

__device__ __forceinline__ cplx cmul(cplx a, cplx b){
  return make_float2(a.x*b.x - a.y*b.y, a.x*b.y + a.y*b.x);
}
__device__ __forceinline__ cplx lc(float a, cplx u, float b, cplx v){
  return make_float2(a*u.x + b*v.x, a*u.y + b*v.y);
}
__device__ __forceinline__ cplx sc(float a, cplx u){ return make_float2(a*u.x, a*u.y); }

struct N1C { float A,B,C,D,E; };
__device__ __forceinline__ N1C noise_coeffs(float g){
  float ga = g*0.3f, gp = g*0.2f, p = g*0.5f;
  N1C n;
  n.A = 1.0f - 2.0f*p/3.0f;
  n.D = 2.0f*p/3.0f;
  n.B = ga*n.A + n.D*(1.0f-ga);
  n.E = n.D*ga + n.A*(1.0f-ga);
  n.C = (1.0f - 4.0f*p/3.0f) * sqrtf(1.0f-ga) * sqrtf(1.0f-gp);
  return n;
}
__device__ __forceinline__ N1C mkadj(N1C n){
  N1C a; a.A=n.A; a.B=n.D; a.C=n.C; a.D=n.B; a.E=n.E; return a;
}

__device__ __forceinline__ int physof(int L){
  int rl = L >> 6;
  int rot = ((rl<<3)|(rl>>3)) & 63;
  return L ^ rot;
}
__device__ __forceinline__ constexpr int KPc(int p){
  return (p < 6) ? (1<<p) : ((1<<p) | (1 << (((p-6)+3)%6)));
}

template<int U>
__device__ __forceinline__ int base_for(int g){
  constexpr int P[6][8] = {
    {0,0,0,0,0,0,0,0},
    {9,10,2,4,5, 3,8,11},   // u=1
    {0,10,11,3,5, 4,6,9},   // u=2
    {0,1,11,6,4, 5,7,10},   // u=3
    {1,2,6,7,5, 0,8,11},    // u=4
    {0,2,3,7,8, 1,6,9}};    // u=5
  int b = 0;
  #pragma unroll
  for (int i=0;i<8;i++) b ^= (-((g>>i)&1)) & KPc(P[U][i]);
  return b;
}

__device__ __forceinline__ void rot_pair(cplx& v0, cplx& v1, float cy, float sy){
  cplx a=v0, b=v1;
  v0 = make_float2(cy*a.x - sy*b.x, cy*a.y - sy*b.y);
  v1 = make_float2(sy*a.x + cy*b.x, sy*a.y + cy*b.y);
}

// ---- agent-scope (MALL-coherent) global accessors ----
__device__ __forceinline__ cplx gload(const cplx* p){
  unsigned long long v = __hip_atomic_load((const unsigned long long*)p,
                                           __ATOMIC_RELAXED, __HIP_MEMORY_SCOPE_AGENT);
  union { unsigned long long u; cplx c; } x; x.u = v; return x.c;
}
__device__ __forceinline__ void gstore(cplx* p, cplx v){
  union { unsigned long long u; cplx c; } x; x.c = v;
  __hip_atomic_store((unsigned long long*)p, x.u, __ATOMIC_RELAXED, __HIP_MEMORY_SCOPE_AGENT);
}
__device__ __forceinline__ void fstore(float* p, float v){
  __hip_atomic_store(p, v, __ATOMIC_RELAXED, __HIP_MEMORY_SCOPE_AGENT);
}
__device__ __forceinline__ float fload(const float* p){
  return __hip_atomic_load(p, __ATOMIC_RELAXED, __HIP_MEMORY_SCOPE_AGENT);
}

// ---- grid barrier: generation counter, agent scope; 16 blocks co-resident ----
__device__ __forceinline__ void gridbar(int* bar, int* gen, int nb){
  __syncthreads();
  if (threadIdx.x == 0){
    __threadfence();
    int g = __hip_atomic_load(gen, __ATOMIC_RELAXED, __HIP_MEMORY_SCOPE_AGENT);
    int a = __hip_atomic_fetch_add(bar, 1, __ATOMIC_ACQ_REL, __HIP_MEMORY_SCOPE_AGENT);
    if (a == nb-1){
      __hip_atomic_store(bar, 0, __ATOMIC_RELAXED, __HIP_MEMORY_SCOPE_AGENT);
      __hip_atomic_fetch_add(gen, 1, __ATOMIC_ACQ_REL, __HIP_MEMORY_SCOPE_AGENT);
    } else {
      while (__hip_atomic_load(gen, __ATOMIC_ACQUIRE, __HIP_MEMORY_SCOPE_AGENT) == g)
        __builtin_amdgcn_s_sleep(2);
    }
    __threadfence();
  }
  __syncthreads();
}

// ---------------- adjoint half-stage: thread owns b=bsel half ----------------
template<int U>
__device__ __forceinline__ void astage_half(cplx* __restrict__ slab, float4 rc,
                                            int bp, int bsel, N1C n1a, N1C n2a,
                                            float al, float be, float ga, float de){
  constexpr int KA=KPc(6+U), KB=KPc(5+U), KC=1<<U, KD=1<<(U-1);
  int bb = bsel ? KB : 0;
  int xn = bsel ? 0 : (KB^KD);
  cplx h[8], X[4];
  #pragma unroll
  for (int i=0;i<8;i++){
    int a=(i>>2)&1, cc=(i>>1)&1, d=i&1;
    h[i] = slab[bp ^ bb ^ (a?KA:0) ^ (cc?KC:0) ^ (d?KD:0)];
  }
  #pragma unroll
  for (int j=0;j<4;j++){
    int a=j>>1, cc=j&1;
    X[j] = slab[bp ^ xn ^ (a?KA:0) ^ (cc?KC:0)];
  }
  cplx p  = make_float2(rc.z, -rc.w);
  cplx pc = make_float2(rc.z,  rc.w);
  float cy=rc.x, sy=-rc.y;
  #pragma unroll
  for (int d=0;d<2;d++){
    cplx t00=h[d], t11=h[6+d];
    h[d]   = lc(n1a.A,t00, n1a.B,t11);
    h[6+d] = lc(n1a.D,t00, n1a.E,t11);
    h[2+d] = cmul(p,  h[2+d]);
    h[4+d] = cmul(pc, h[4+d]);
  }
  #pragma unroll
  for (int a=0;a<2;a++)
    #pragma unroll
    for (int d=0;d<2;d++) rot_pair(h[a*4+d], h[a*4+2+d], cy, sy);
  #pragma unroll
  for (int cc=0;cc<2;cc++)
    #pragma unroll
    for (int d=0;d<2;d++) rot_pair(h[cc*2+d], h[4+cc*2+d], cy, sy);
  {
    cplx t00=X[0], t11=X[3];
    X[0]=lc(n1a.A,t00, n1a.B,t11);
    X[3]=lc(n1a.D,t00, n1a.E,t11);
    X[1]=cmul(p,X[1]); X[2]=cmul(pc,X[2]);
    rot_pair(X[0],X[1],cy,sy); rot_pair(X[2],X[3],cy,sy);
    rot_pair(X[0],X[2],cy,sy); rot_pair(X[1],X[3],cy,sy);
  }
  #pragma unroll
  for (int j=0;j<4;j++){
    h[2*j]   = lc(al, h[2*j],   be, X[j]);
    h[2*j+1] = lc(ga, h[2*j+1], de, X[j]);
  }
  #pragma unroll
  for (int d=0;d<2;d++){
    cplx t00=h[d], t11=h[6+d];
    h[d]   = lc(n2a.A,t00, n2a.B,t11);
    h[6+d] = lc(n2a.D,t00, n2a.E,t11);
    h[2+d] = sc(n2a.C, h[2+d]);
    h[4+d] = sc(n2a.C, h[4+d]);
  }
  #pragma unroll
  for (int i=0;i<8;i++){
    int a=(i>>2)&1, cc=(i>>1)&1, d=i&1;
    slab[bp ^ (a?KA:0) ^ ((bsel^a)?KB:0) ^ (cc?KC:0) ^ ((d^cc)?KD:0)] = h[i];
  }
}

// ---------------- R7 stage: full-16 duplicate compute, write own half ----------------
template<int U>
__device__ __forceinline__ void astage_r7full(cplx* __restrict__ slab, float4 rc, float4 rc7,
                                              int bp, int bsel, N1C n1a, N1C n2a){
  constexpr int KA=KPc(6+U), KB=KPc(5+U), KC=1<<U, KD=1<<(U-1);
  cplx h[16];
  #pragma unroll
  for (int idx=0; idx<16; idx++){
    int a=(idx>>3)&1, b=(idx>>2)&1, cc=(idx>>1)&1, d=idx&1;
    h[idx] = slab[bp ^ (a?KA:0) ^ (b?KB:0) ^ (cc?KC:0) ^ (d?KD:0)];
  }
  {
    cplx p=make_float2(rc7.z,-rc7.w), pc=make_float2(rc7.z,rc7.w);
    #pragma unroll
    for (int a=0;a<2;a++)
      #pragma unroll
      for (int cc=0;cc<2;cc++){
        int i=(a<<3)|(cc<<1);
        cplx t00=h[i], t11=h[i|5];
        h[i]   = lc(n1a.A,t00, n1a.B,t11);
        h[i|5] = lc(n1a.D,t00, n1a.E,t11);
        h[i|1] = cmul(p,  h[i|1]);
        h[i|4] = cmul(pc, h[i|4]);
      }
    float cy=rc7.x, sy=-rc7.y;
    #pragma unroll
    for (int a=0;a<2;a++)
      #pragma unroll
      for (int b=0;b<2;b++)
        #pragma unroll
        for (int cc=0;cc<2;cc++){
          int i=(a<<3)|(b<<2)|(cc<<1);
          rot_pair(h[i], h[i|1], cy, sy);
        }
    #pragma unroll
    for (int a=0;a<2;a++)
      #pragma unroll
      for (int cc=0;cc<2;cc++)
        #pragma unroll
        for (int d=0;d<2;d++){
          int i=(a<<3)|(cc<<1)|d;
          rot_pair(h[i], h[i|4], cy, sy);
        }
  }
  {
    cplx p=make_float2(rc.z,-rc.w), pc=make_float2(rc.z,rc.w);
    #pragma unroll
    for (int b=0;b<2;b++)
      #pragma unroll
      for (int d=0;d<2;d++){
        int i=(b<<2)|d;
        cplx t00=h[i], t11=h[i|10];
        h[i]    = lc(n1a.A,t00, n1a.B,t11);
        h[i|10] = lc(n1a.D,t00, n1a.E,t11);
        h[i|2]  = cmul(p,  h[i|2]);
        h[i|8]  = cmul(pc, h[i|8]);
      }
    float cy=rc.x, sy=-rc.y;
    #pragma unroll
    for (int a=0;a<2;a++)
      #pragma unroll
      for (int b=0;b<2;b++)
        #pragma unroll
        for (int d=0;d<2;d++){
          int i=(a<<3)|(b<<2)|d;
          rot_pair(h[i], h[i|2], cy, sy);
        }
    #pragma unroll
    for (int b=0;b<2;b++)
      #pragma unroll
      for (int cc=0;cc<2;cc++)
        #pragma unroll
        for (int d=0;d<2;d++){
          int i=(b<<2)|(cc<<1)|d;
          rot_pair(h[i], h[i|8], cy, sy);
        }
  }
  #pragma unroll
  for (int a=0;a<2;a++)
    #pragma unroll
    for (int cc=0;cc<2;cc++){
      int i=(a<<3)|(cc<<1);
      cplx t00=h[i], t11=h[i|5];
      h[i]   = lc(n2a.A,t00, n2a.B,t11);
      h[i|5] = lc(n2a.D,t00, n2a.E,t11);
      h[i|1] = sc(n2a.C, h[i|1]);
      h[i|4] = sc(n2a.C, h[i|4]);
    }
  #pragma unroll
  for (int b=0;b<2;b++)
    #pragma unroll
    for (int d=0;d<2;d++){
      int i=(b<<2)|d;
      cplx t00=h[i], t11=h[i|10];
      h[i]    = lc(n2a.A,t00, n2a.B,t11);
      h[i|10] = lc(n2a.D,t00, n2a.E,t11);
      h[i|2]  = sc(n2a.C, h[i|2]);
      h[i|8]  = sc(n2a.C, h[i|8]);
    }
  #pragma unroll
  for (int idx=0; idx<16; idx++){
    int a=(idx>>3)&1, b=(idx>>2)&1, cc=(idx>>1)&1, d=idx&1;
    if (b == bsel)
      slab[bp ^ (a?KA:0) ^ ((b^a)?KB:0) ^ (cc?KC:0) ^ ((d^cc)?KD:0)] = h[idx];
  }
}

#define ASTG(l,q,u)  astage_half<u>(slab, sS[(l)*8+(q)], b##u, bsel, n1a, n2a, al,be,ga,de); __syncthreads();
#define ASTG7(l,q,u) astage_r7full<u>(slab, sS[(l)*8+(q)], sS[(l)*8+7], b##u, bsel, n1a, n2a); __syncthreads();

// ---------------- the whole pipeline in one kernel ----------------
__global__ __launch_bounds__(512) void fused_kernel(const float* __restrict__ x,
                                                    const float* __restrict__ w,
                                                    cplx* __restrict__ buf0,
                                                    cplx* __restrict__ buf1,
                                                    float* __restrict__ partial,
                                                    int* bar, int* gen,
                                                    float* __restrict__ out){
  __shared__ cplx slab[4096];
  __shared__ float4 sS[48];
  __shared__ float smAll[1024];   // [sample][qubit*4 + r*2 + c]
  __shared__ float red[512];
  int t = threadIdx.x; int bsel = t & 1; int gg = t >> 1;
  int blk = blockIdx.x;
  N1C n1a = mkadj(noise_coeffs(0.0003f));
  N1C n2a = mkadj(noise_coeffs(0.0065f));
  float al = bsel ? n2a.C : n2a.A;
  float be = bsel ? 0.f   : n2a.B;
  float ga = bsel ? n2a.E : n2a.C;
  float de = bsel ? n2a.D : 0.f;
  int b1=base_for<1>(gg), b2=base_for<2>(gg), b3=base_for<3>(gg),
      b4=base_for<4>(gg), b5=base_for<5>(gg);
  (void)b1;(void)b2;(void)b3;(void)b4;(void)b5;

  // constants: stage float4s + all 32 samples' encode 2x2s
  if (t < 48){
    N1C n1 = noise_coeffs(0.0003f);
    float w0=w[t*2], w1=w[t*2+1];
    sS[t] = make_float4(cosf(0.5f*w0), sinf(0.5f*w0), n1.C*cosf(w1), -n1.C*sinf(w1));
  }
  if (t < 256){
    int s = t>>3, q = t&7;
    N1C n1 = noise_coeffs(0.0003f);
    float xv = x[s*8+q];
    float c = cosf(0.5f*xv), sn = sinf(0.5f*xv);
    float p00=c*c, p01=c*sn, p11=sn*sn;
    float* mm = &smAll[s*32 + q*4];
    mm[0]=n1.A*p00+n1.B*p11; mm[1]=n1.C*p01; mm[2]=n1.C*p01; mm[3]=n1.D*p00+n1.E*p11;
  }
  __syncthreads();

  // ---- phase D: 4 diagonal W1 tiles, Z0 init, 5 stages ----
  if (blk < 4){
    int oB = blk*5;
    float sgn = ((oB>>2)&2) ? -1.f : 1.f;
    #pragma unroll
    for (int k=0;k<8;k++){
      int L=(k<<9)|t, rl=L>>6, cl=L&63;
      slab[physof(L)] = make_float2((rl==cl)?sgn:0.f, 0.f);
    }
    __syncthreads();
    ASTG7(5,6,1) ASTG(5,5,2) ASTG(5,4,3) ASTG7(4,6,1) ASTG(4,5,2)
    cplx* go = buf0 + oB*4096;
    #pragma unroll
    for (int k=0;k<8;k++){ int L=(k<<9)|t; gstore(&go[L], slab[physof(L)]); }
  }
  gridbar(bar, gen, 16);

  // ---- phase C: W2 window, reads W1 diag tiles, 8 stages ----
  {
    int oC=blk, oCr=oC>>2, oCc=oC&3;
    #pragma unroll
    for (int j=0;j<8;j++){
      int f=(j<<9)|t, mI=f>>8, told=f&255;
      int xx=told>>4, y=told&15;
      cplx v = ((mI>>2)==(mI&3))
             ? gload(&buf0[mI*4096 + (((xx<<2)|oCr)<<6) + ((y<<2)|oCc)])
             : make_float2(0.f,0.f);
      int rlC=((mI>>2)<<4)|xx, clC=((mI&3)<<4)|y;
      slab[physof((rlC<<6)|clC)] = v;
    }
    __syncthreads();
    ASTG(5,3,2) ASTG(5,2,3) ASTG(5,1,4) ASTG(5,0,5)
    ASTG(4,4,1) ASTG(4,3,2) ASTG(4,2,3) ASTG(4,1,4)
    cplx* go = buf1 + oC*4096;
    #pragma unroll
    for (int k=0;k<8;k++){ int L=(k<<9)|t; gstore(&go[L], slab[physof(L)]); }
  }
  gridbar(bar, gen, 16);

  // ---- phase B: W1 window, reads W2, 14 stages ----
  {
    int oB=blk, r67=oB>>2, c67=oB&3;
    #pragma unroll
    for (int j=0;j<8;j++){
      int f=(j<<9)|t, mI=f>>8, told=f&255;
      cplx v = gload(&buf1[mI*4096 + (((r67<<4)|(told>>4))<<6) + ((c67<<4)|(told&15))]);
      int rlB=((told>>4)<<2)|(mI>>2), clB=((told&15)<<2)|(mI&3);
      slab[physof((rlB<<6)|clB)] = v;
    }
    __syncthreads();
    ASTG7(3,6,1) ASTG(3,5,2) ASTG(3,4,3) ASTG(3,3,4) ASTG(3,2,5)
    ASTG7(2,6,1) ASTG(2,5,2) ASTG(2,4,3) ASTG(2,3,4)
    ASTG7(1,6,1) ASTG(1,5,2) ASTG(1,4,3)
    ASTG7(0,6,1) ASTG(0,5,2)
    cplx* go = buf0 + oB*4096;
    #pragma unroll
    for (int k=0;k<8;k++){ int L=(k<<9)|t; gstore(&go[L], slab[physof(L)]); }
  }
  gridbar(bar, gen, 16);

  // ---- phase A: W2 window, reads W1, 15 stages; tile stays in LDS ----
  {
    int oC=blk, oCr=oC>>2, oCc=oC&3;
    #pragma unroll
    for (int j=0;j<8;j++){
      int f=(j<<9)|t, mI=f>>8, told=f&255;
      int xx=told>>4, y=told&15;
      cplx v = gload(&buf0[mI*4096 + (((xx<<2)|oCr)<<6) + ((y<<2)|oCc)]);
      int rlC=((mI>>2)<<4)|xx, clC=((mI&3)<<4)|y;
      slab[physof((rlC<<6)|clC)] = v;
    }
    __syncthreads();
    ASTG(4,0,5)
    ASTG(3,1,4) ASTG(3,0,5)
    ASTG(2,2,3) ASTG(2,1,4) ASTG(2,0,5)
    ASTG(1,3,2) ASTG(1,2,3) ASTG(1,1,4) ASTG(1,0,5)
    ASTG(0,4,1) ASTG(0,3,2) ASTG(0,2,3) ASTG(0,1,4) ASTG(0,0,5)
  }

  // ---- expectation: contract this block's W2 tile with all 32 product states ----
  {
    int s = t & 31, g = t >> 5;              // sample, element group
    const float* ms = &smAll[s*32];
    int oCr = blk>>2, oCc = blk&3;
    float w67 = ms[24 + (oCr>>1)*2 + (oCc>>1)] * ms[28 + (oCr&1)*2 + (oCc&1)];
    float P0[2] = { ms[((g>>3)&1)*2 + 0],      ms[((g>>3)&1)*2 + 1] };
    float P1[2] = { ms[4 + ((g>>2)&1)*2 + 0],  ms[4 + ((g>>2)&1)*2 + 1] };
    float P2[2] = { ms[8 + ((g>>1)&1)*2 + 0],  ms[8 + ((g>>1)&1)*2 + 1] };
    float P3[2] = { ms[12 + (g&1)*2 + 0],      ms[12 + (g&1)*2 + 1] };
    float M4[4] = { ms[16], ms[17], ms[18], ms[19] };   // [r*2+c]
    float M5[4] = { ms[20], ms[21], ms[22], ms[23] };
    float acc = 0.f;
    #pragma unroll
    for (int hi=0; hi<16; hi++){
      float wq = w67 * P0[(hi>>3)&1] * P1[(hi>>2)&1] * P2[(hi>>1)&1] * P3[hi&1];
      #pragma unroll
      for (int r01=0; r01<4; r01++){
        int rl = (g<<2)|r01;
        #pragma unroll
        for (int lo=0; lo<4; lo++){
          int cl = (hi<<2)|lo;
          float wgt = wq * M4[((r01>>1)<<1)|(lo>>1)] * M5[((r01&1)<<1)|(lo&1)];
          acc += slab[physof((rl<<6)|cl)].x * wgt;
        }
      }
    }
    red[t] = acc;
  }
  __syncthreads();
  if (t < 32){
    float v = 0.f;
    #pragma unroll
    for (int g2=0; g2<16; g2++) v += red[t | (g2<<5)];
    fstore(&partial[blk*32 + t], v);
  }
  gridbar(bar, gen, 16);

  // ---- final deterministic reduce on block 0 ----
  if (blk == 0 && t < 32){
    float v = 0.f;
    #pragma unroll
    for (int b=0;b<16;b++) v += fload(&partial[b*32 + t]);
    out[t] = v;
  }
}

extern "C" void kernel_launch(void* const* d_in, const int* in_sizes, int n_in,
                              void* d_out, int out_size, void* d_ws, size_t ws_size,
                              hipStream_t stream) {
  const float* x = (const float*)d_in[0];   // [32,8]
  const float* w = (const float*)d_in[1];   // [6,8,2]
  float* out = (float*)d_out;               // [32,1] f32
  char* ws = (char*)d_ws;

  cplx*  buf0    = (cplx*)ws;                           // 512 KB (W1 layout)
  cplx*  buf1    = (cplx*)(ws + (size_t)1048576);       // 512 KB (W2 layout)
  float* partial = (float*)(ws + (size_t)2097152);      // 2 KB
  int*   bar     = (int*)(ws + (size_t)2097152 + 4096); // bar, gen

  hipMemsetAsync(bar, 0, 8, stream);
  fused_kernel<<<16, 512, 0, stream>>>(x, w, buf0, buf1, partial, bar, bar+1, out);
}

// Round 9
// 43.127 us; speedup vs baseline: 1.8477x; 1.8477x over previous
//
#include <hip/hip_runtime.h>
#include <cmath>

// Noisy 8-qubit density-matrix sim, batch 32, depth 6 — backward-LIGHTCONE adjoint.
// E_b = Tr(Λ†(Z0)·rho_b). All channels CPTP => adjoints unital => stages with
// qubits outside O's support act as identity. Reversed circuit from Z0:
//   l=5: T†(0,5); l=4: T†(1,4),T†(0,4); ... l=1: T†(4..0,1)  -> support {0..5} (4096 els)
//   l=0: T†(5,0) expands to {0..6} (16384 els), then T†(4..0,0) block-diag in qubit 6.
// Qubit 7 NEVER enters (its trace factor is exactly 1). 21 nontrivial stages total.
// ONE 1024-thread block does the whole backward pass in LDS (32KB slab then 128KB),
// writes Re(O) (64KB) to global; a 32-block kernel contracts with product states.
// Stage internals (astage_half pair-split, adjoint order, split tables) verbatim
// from the round-6/7 kernels that passed with absmax 0.

typedef float2 cplx;
#define BATCH 32

__device__ __forceinline__ cplx cmul(cplx a, cplx b){
  return make_float2(a.x*b.x - a.y*b.y, a.x*b.y + a.y*b.x);
}
__device__ __forceinline__ cplx lc(float a, cplx u, float b, cplx v){
  return make_float2(a*u.x + b*v.x, a*u.y + b*v.y);
}
__device__ __forceinline__ cplx sc(float a, cplx u){ return make_float2(a*u.x, a*u.y); }

struct N1C { float A,B,C,D,E; };
__device__ __forceinline__ N1C noise_coeffs(float g){
  float ga = g*0.3f, gp = g*0.2f, p = g*0.5f;
  N1C n;
  n.A = 1.0f - 2.0f*p/3.0f;
  n.D = 2.0f*p/3.0f;
  n.B = ga*n.A + n.D*(1.0f-ga);
  n.E = n.D*ga + n.A*(1.0f-ga);
  n.C = (1.0f - 4.0f*p/3.0f) * sqrtf(1.0f-ga) * sqrtf(1.0f-gp);
  return n;
}
__device__ __forceinline__ N1C mkadj(N1C n){
  N1C a; a.A=n.A; a.B=n.D; a.C=n.C; a.D=n.B; a.E=n.E; return a;
}

// swizzle within each 4096-el (12-bit) sub-slab: phys = L ^ rot-left-3(row-local)
__device__ __forceinline__ int physof(int L){
  int rl = L >> 6;
  int rot = ((rl<<3)|(rl>>3)) & 63;
  return L ^ rot;
}
__device__ __forceinline__ constexpr int KPc(int p){
  return (p < 6) ? (1<<p) : ((1<<p) | (1 << (((p-6)+3)%6)));
}

// pair-split free-bit tables (round-4/7, bank-checked)
template<int U>
__device__ __forceinline__ int base_for(int g){
  constexpr int P[6][8] = {
    {0,0,0,0,0,0,0,0},
    {9,10,2,4,5, 3,8,11},   // u=1
    {0,10,11,3,5, 4,6,9},   // u=2
    {0,1,11,6,4, 5,7,10},   // u=3
    {1,2,6,7,5, 0,8,11},    // u=4
    {0,2,3,7,8, 1,6,9}};    // u=5
  int b = 0;
  #pragma unroll
  for (int i=0;i<8;i++) b ^= (-((g>>i)&1)) & KPc(P[U][i]);
  return b;
}

// free bits for the special T†(5,0) stage (10 bits over positions <=11);
// lane bits t0..t3 -> masks with low-4 {2,4,8,1} => conflict-free coverage
__device__ __forceinline__ int base_s(int t){
  constexpr int P[10] = {1,2,3,9, 4,5,7,8,10,11};
  int b = 0;
  #pragma unroll
  for (int i=0;i<10;i++) b ^= (-((t>>i)&1)) & KPc(P[i]);
  return b;
}

__device__ __forceinline__ void rot_pair(cplx& v0, cplx& v1, float cy, float sy){
  cplx a=v0, b=v1;
  v0 = make_float2(cy*a.x - sy*b.x, cy*a.y - sy*b.y);
  v1 = make_float2(sy*a.x + cy*b.x, sy*a.y + cy*b.y);
}

// ---------------- adjoint half-stage (pair-split on row-tgt bit b) — round-7 verbatim ----------------
template<int U>
__device__ __forceinline__ void astage_half(cplx* __restrict__ slab, float4 rc,
                                            int bp, int bsel, N1C n1a, N1C n2a,
                                            float al, float be, float ga, float de){
  constexpr int KA=KPc(6+U), KB=KPc(5+U), KC=1<<U, KD=1<<(U-1);
  int bb = bsel ? KB : 0;
  int xn = bsel ? 0 : (KB^KD);
  cplx h[8], X[4];
  #pragma unroll
  for (int i=0;i<8;i++){
    int a=(i>>2)&1, cc=(i>>1)&1, d=i&1;
    h[i] = slab[bp ^ bb ^ (a?KA:0) ^ (cc?KC:0) ^ (d?KD:0)];
  }
  #pragma unroll
  for (int j=0;j<4;j++){
    int a=j>>1, cc=j&1;
    X[j] = slab[bp ^ xn ^ (a?KA:0) ^ (cc?KC:0)];
  }
  cplx p  = make_float2(rc.z, -rc.w);
  cplx pc = make_float2(rc.z,  rc.w);
  float cy=rc.x, sy=-rc.y;
  #pragma unroll
  for (int d=0;d<2;d++){
    cplx t00=h[d], t11=h[6+d];
    h[d]   = lc(n1a.A,t00, n1a.B,t11);
    h[6+d] = lc(n1a.D,t00, n1a.E,t11);
    h[2+d] = cmul(p,  h[2+d]);
    h[4+d] = cmul(pc, h[4+d]);
  }
  #pragma unroll
  for (int a=0;a<2;a++)
    #pragma unroll
    for (int d=0;d<2;d++) rot_pair(h[a*4+d], h[a*4+2+d], cy, sy);
  #pragma unroll
  for (int cc=0;cc<2;cc++)
    #pragma unroll
    for (int d=0;d<2;d++) rot_pair(h[cc*2+d], h[4+cc*2+d], cy, sy);
  {
    cplx t00=X[0], t11=X[3];
    X[0]=lc(n1a.A,t00, n1a.B,t11);
    X[3]=lc(n1a.D,t00, n1a.E,t11);
    X[1]=cmul(p,X[1]); X[2]=cmul(pc,X[2]);
    rot_pair(X[0],X[1],cy,sy); rot_pair(X[2],X[3],cy,sy);
    rot_pair(X[0],X[2],cy,sy); rot_pair(X[1],X[3],cy,sy);
  }
  #pragma unroll
  for (int j=0;j<4;j++){
    h[2*j]   = lc(al, h[2*j],   be, X[j]);
    h[2*j+1] = lc(ga, h[2*j+1], de, X[j]);
  }
  #pragma unroll
  for (int d=0;d<2;d++){
    cplx t00=h[d], t11=h[6+d];
    h[d]   = lc(n2a.A,t00, n2a.B,t11);
    h[6+d] = lc(n2a.D,t00, n2a.E,t11);
    h[2+d] = sc(n2a.C, h[2+d]);
    h[4+d] = sc(n2a.C, h[4+d]);
  }
  #pragma unroll
  for (int i=0;i<8;i++){
    int a=(i>>2)&1, cc=(i>>1)&1, d=i&1;
    slab[bp ^ (a?KA:0) ^ ((bsel^a)?KB:0) ^ (cc?KC:0) ^ ((d^cc)?KD:0)] = h[i];
  }
}

// ---------------- full-16 adjoint stage, general masks (round-6 do_stage_adj, no R7) ----------------
template<int KA,int KB,int KC,int KD>
__device__ __forceinline__ void astage_full(cplx* __restrict__ slab, float4 rc,
                                            int bp, N1C n1a, N1C n2a){
  cplx h[16];
  #pragma unroll
  for (int idx=0; idx<16; idx++){
    int a=(idx>>3)&1, b=(idx>>2)&1, cc=(idx>>1)&1, d=idx&1;
    h[idx] = slab[bp ^ (a?KA:0) ^ (b?KB:0) ^ (cc?KC:0) ^ (d?KD:0)];
  }
  // Rctl† on (a,cc): sparse adjoint then Y(-θ)
  {
    cplx p=make_float2(rc.z,-rc.w), pc=make_float2(rc.z,rc.w);
    #pragma unroll
    for (int b=0;b<2;b++)
      #pragma unroll
      for (int d=0;d<2;d++){
        int i=(b<<2)|d;
        cplx t00=h[i], t11=h[i|10];
        h[i]    = lc(n1a.A,t00, n1a.B,t11);
        h[i|10] = lc(n1a.D,t00, n1a.E,t11);
        h[i|2]  = cmul(p,  h[i|2]);
        h[i|8]  = cmul(pc, h[i|8]);
      }
    float cy=rc.x, sy=-rc.y;
    #pragma unroll
    for (int a=0;a<2;a++)
      #pragma unroll
      for (int b=0;b<2;b++)
        #pragma unroll
        for (int d=0;d<2;d++){
          int i=(a<<3)|(b<<2)|d;
          rot_pair(h[i], h[i|2], cy, sy);
        }
    #pragma unroll
    for (int b=0;b<2;b++)
      #pragma unroll
      for (int cc=0;cc<2;cc++)
        #pragma unroll
        for (int d=0;d<2;d++){
          int i=(b<<2)|(cc<<1)|d;
          rot_pair(h[i], h[i|8], cy, sy);
        }
  }
  // N2t† on (b,d)
  #pragma unroll
  for (int a=0;a<2;a++)
    #pragma unroll
    for (int cc=0;cc<2;cc++){
      int i=(a<<3)|(cc<<1);
      cplx t00=h[i], t11=h[i|5];
      h[i]   = lc(n2a.A,t00, n2a.B,t11);
      h[i|5] = lc(n2a.D,t00, n2a.E,t11);
      h[i|1] = sc(n2a.C, h[i|1]);
      h[i|4] = sc(n2a.C, h[i|4]);
    }
  // N2c† on (a,cc)
  #pragma unroll
  for (int b=0;b<2;b++)
    #pragma unroll
    for (int d=0;d<2;d++){
      int i=(b<<2)|d;
      cplx t00=h[i], t11=h[i|10];
      h[i]    = lc(n2a.A,t00, n2a.B,t11);
      h[i|10] = lc(n2a.D,t00, n2a.E,t11);
      h[i|2]  = sc(n2a.C, h[i|2]);
      h[i|8]  = sc(n2a.C, h[i|8]);
    }
  // scatter with CNOT fold
  #pragma unroll
  for (int idx=0; idx<16; idx++){
    int a=(idx>>3)&1, b=(idx>>2)&1, cc=(idx>>1)&1, d=idx&1;
    slab[bp ^ (a?KA:0) ^ ((b^a)?KB:0) ^ (cc?KC:0) ^ ((d^cc)?KD:0)] = h[idx];
  }
}

#define ASTGa(l,q,u) { if (t < 512) astage_half<u>(slab, sS[(l)*8+(q)], b##u, bsel, n1a, n2a, al,be,ga,de); __syncthreads(); }
#define ASTGb(q,u)   { astage_half<u>(slab + (subA<<12), sS[(q)], b##u, bsel, n1a, n2a, al,be,ga,de); \
                       astage_half<u>(slab + (subB<<12), sS[(q)], b##u, bsel, n1a, n2a, al,be,ga,de); __syncthreads(); }

// ---------------- backward pass: one block, 1024 threads ----------------
__global__ __launch_bounds__(1024) void backward_kernel(const float* __restrict__ w,
                                                        float* __restrict__ Og){
  __shared__ cplx slab[16384];      // 128 KB: 4 sub-blocks (r6,c6) x 4096
  __shared__ float4 sS[48];
  int t = threadIdx.x;
  int bsel = t & 1;
  int gg = (t >> 1) & 255;
  int subA = (t >> 9) & 1, subB = subA | 2;
  N1C n1a = mkadj(noise_coeffs(0.0003f));
  N1C n2a = mkadj(noise_coeffs(0.0065f));
  float al = bsel ? n2a.C : n2a.A;
  float be = bsel ? 0.f   : n2a.B;
  float ga = bsel ? n2a.E : n2a.C;
  float de = bsel ? n2a.D : 0.f;
  int b1=base_for<1>(gg), b2=base_for<2>(gg), b3=base_for<3>(gg),
      b4=base_for<4>(gg), b5=base_for<5>(gg);
  (void)b1;(void)b2;(void)b3;(void)b4;(void)b5;

  if (t < 48){
    N1C n1 = noise_coeffs(0.0003f);
    float w0=w[t*2], w1=w[t*2+1];
    sS[t] = make_float4(cosf(0.5f*w0), sinf(0.5f*w0), n1.C*cosf(w1), -n1.C*sinf(w1));
  }
  // init O = Z0 ⊗ I on 6-qubit slab (qubit0 = row bit 5)
  #pragma unroll
  for (int i=0;i<4;i++){
    int L = i*1024 + t, rl = L>>6, cl = L&63;
    slab[physof(L)] = make_float2((rl==cl) ? ((rl&32)? -1.f : 1.f) : 0.f, 0.f);
  }
  __syncthreads();

  // layers 5..1: 15 nontrivial stages on the 4096-el slab (U = 5-q)
  ASTGa(5,0,5)
  ASTGa(4,1,4) ASTGa(4,0,5)
  ASTGa(3,2,3) ASTGa(3,1,4) ASTGa(3,0,5)
  ASTGa(2,3,2) ASTGa(2,2,3) ASTGa(2,1,4) ASTGa(2,0,5)
  ASTGa(1,4,1) ASTGa(1,3,2) ASTGa(1,2,3) ASTGa(1,1,4) ASTGa(1,0,5)

  // expand to 7 qubits: O ⊗ I_q6 -> sub(0,0)=sub(1,1)=old, off-diag = 0
  #pragma unroll
  for (int i=0;i<4;i++){
    int e = i*1024 + t;
    cplx v = slab[e];
    slab[(3<<12)|e] = v;
    slab[(1<<12)|e] = make_float2(0.f,0.f);
    slab[(2<<12)|e] = make_float2(0.f,0.f);
  }
  __syncthreads();

  // T†(5,0): couples qubit5 (ctl: row pos6 / col pos0) with qubit6 (tgt: bits 13/12)
  astage_full<KPc(6), (1<<13), 1, (1<<12)>(slab, sS[5], base_s(t), n1a, n2a);
  __syncthreads();

  // T†(4..0,0): block-diagonal in qubit 6 -> per-sub-block 12-bit stages
  ASTGb(4,1) ASTGb(3,2) ASTGb(2,3) ASTGb(1,4) ASTGb(0,5)

  // write Re(O): Og[sub*4096 + L12]
  #pragma unroll
  for (int i=0;i<16;i++){
    int el = i*1024 + t;
    Og[el] = slab[(el & (3<<12)) | physof(el & 4095)].x;
  }
}

// ---------------- contraction: E_b = sum O[r,c] * prod_q m_q[r_q,c_q]  (tr over q7 = 1) ----------------
__global__ __launch_bounds__(256) void contract_kernel(const float* __restrict__ Og,
                                                       const float* __restrict__ x,
                                                       float* __restrict__ out){
  __shared__ float sm[28];   // qubits 0..6 encode 2x2s
  __shared__ float red[4];
  int t = threadIdx.x, s = blockIdx.x;
  if (t < 7){
    N1C n1 = noise_coeffs(0.0003f);
    float xv = x[s*8+t];
    float c = cosf(0.5f*xv), sn = sinf(0.5f*xv);
    float p00=c*c, p01=c*sn, p11=sn*sn;
    sm[t*4+0]=n1.A*p00+n1.B*p11; sm[t*4+1]=n1.C*p01;
    sm[t*4+2]=n1.C*p01;          sm[t*4+3]=n1.D*p00+n1.E*p11;
  }
  __syncthreads();
  int cl = t & 63;           // col bits (qubit q <-> bit 5-q)
  int r45 = t >> 6;          // row bits of qubits 4,5
  float w0;
  {
    int c4=(cl>>1)&1, c5=cl&1;
    w0 = sm[16 + ((r45>>1)&1)*2 + c4] * sm[20 + (r45&1)*2 + c5];
  }
  int c0=(cl>>5)&1, c1=(cl>>4)&1, c2=(cl>>3)&1, c3=(cl>>2)&1;
  float g0[2]={sm[0+c0],  sm[2+c0]};
  float g1[2]={sm[4+c1],  sm[6+c1]};
  float g2[2]={sm[8+c2],  sm[10+c2]};
  float g3[2]={sm[12+c3], sm[14+c3]};
  float m6v[4]={sm[24], sm[25], sm[26], sm[27]};
  float acc = 0.f;
  #pragma unroll
  for (int i=0;i<64;i++){
    int el = i*256 + t;     // sub=i>>4; rl bits5..2 = i bits3..0; rl bits1..0 = r45
    float wq = w0 * g0[(i>>3)&1] * g1[(i>>2)&1] * g2[(i>>1)&1] * g3[i&1] * m6v[i>>4];
    acc += Og[el] * wq;
  }
  #pragma unroll
  for (int off=32; off>0; off>>=1) acc += __shfl_down(acc, off, 64);
  if ((t&63)==0) red[t>>6] = acc;
  __syncthreads();
  if (t==0) out[s] = red[0]+red[1]+red[2]+red[3];
}

extern "C" void kernel_launch(void* const* d_in, const int* in_sizes, int n_in,
                              void* d_out, int out_size, void* d_ws, size_t ws_size,
                              hipStream_t stream) {
  const float* x = (const float*)d_in[0];   // [32,8]
  const float* w = (const float*)d_in[1];   // [6,8,2]
  float* out = (float*)d_out;               // [32,1] f32
  float* Og  = (float*)d_ws;                // 64 KB: Re(O), 7-qubit operator

  backward_kernel<<<1, 1024, 0, stream>>>(w, Og);
  contract_kernel<<<BATCH, 256, 0, stream>>>(Og, x, out);
}